// Round 13
// baseline (626.657 us; speedup 1.0000x reference)
//
#include <hip/hip_runtime.h>
#include <stdint.h>

typedef unsigned int u32;
typedef unsigned long long u64;
typedef _Float16 f16x8 __attribute__((ext_vector_type(8)));
typedef float f32x4 __attribute__((ext_vector_type(4)));

#define HF 96
#define HW 9216           // 96*96
#define CIN 1024
#define CMID 512
#define NA 82944          // HW*9
#define PRE 12000
#define POST 300
#define NW 188            // ceil(PRE/64)
#define NBLK 324          // NA/256
#define OUT_POOL (POST*CIN*49)

// base anchors, exact per np.round (banker's) of the reference generator
__device__ __constant__ float BA[9][4] = {
  {-84.f,-40.f,99.f,55.f}, {-176.f,-88.f,191.f,103.f}, {-360.f,-184.f,375.f,199.f},
  {-56.f,-56.f,71.f,71.f}, {-120.f,-120.f,135.f,135.f}, {-248.f,-248.f,263.f,263.f},
  {-36.f,-80.f,51.f,95.f}, {-80.f,-168.f,95.f,183.f},  {-168.f,-344.f,183.f,359.f}
};

__device__ __forceinline__ u32 fkey(float f) {
  u32 u = __float_as_uint(f);
  return (u & 0x80000000u) ? ~u : (u | 0x80000000u);
}

__device__ __forceinline__ void gl_lds16(const void* g, void* l) {
  __builtin_amdgcn_global_load_lds((const __attribute__((address_space(1))) void*)g,
                                   (__attribute__((address_space(3))) void*)l, 16, 0, 0);
}

// ---------------- P1: feat -> swizzled fp16 hi/lo image with halo (coalesced) ----------------
__global__ void prep_img(const float* __restrict__ feat, f16x8* __restrict__ img)
{
  __shared__ float ls[32][100];
  const int yy = blockIdx.x;
  const int kt = blockIdx.y;
  const int tid = threadIdx.x;
  const int y = yy - 1;
  const bool yok = (unsigned)y < 96u;
  if (yok) {
    for (int e = tid; e < 3072; e += 256) {
      const int ci = e / 96;
      const int x = e - ci * 96;
      ls[ci][x] = feat[(size_t)(kt*32 + ci)*HW + y*96 + x];
    }
  }
  __syncthreads();
  for (int idx = tid; idx < 784; idx += 256) {
    const int col = idx >> 3;
    const int q = idx & 7;
    const int x = col - 1;
    f16x8 val;
#pragma unroll
    for (int i=0;i<8;i++) val[i] = (_Float16)0.f;
    if (yok && (unsigned)x < 96u) {
#pragma unroll
      for (int i=0;i<8;i++) {
        const float v = ls[(q&3)*8 + i][x];
        if (q < 4) val[i] = (_Float16)v;
        else { const _Float16 hi = (_Float16)v; val[i] = (_Float16)((v - (float)hi)*1024.f); }
      }
    }
    const int sw = (col + 2*y) & 7;
    img[(size_t)((kt*98 + yy)*98 + col)*8 + (q ^ sw)] = val;
  }
}

// ---------------- P2: weights -> frag-ready hi/lo (x64 pre-scale), LDS-coalesced ----------------
__global__ void prep_w(const float* __restrict__ w, f16x8* __restrict__ wbuf)
{
  __shared__ float ls[64*289];
  const int co0 = blockIdx.x * 64;
  const int cic0 = blockIdx.y * 4;
  const int tid = threadIdx.x;
  for (int e = tid; e < 64*288; e += 256) {
    const int co = e / 288;
    const int off = e - co*288;
    ls[co*289 + off] = w[(size_t)(co0+co)*9216 + cic0*72 + off];
  }
  __syncthreads();
  const int co = tid & 63;
  for (int task = tid >> 6; task < 36; task += 4) {
    const int cic_l = task / 9;
    const int tap = task - cic_l*9;
    const int cic = cic0 + cic_l;
    const int kt = cic >> 2, kg = cic & 3;
    f16x8 hv, lv;
#pragma unroll
    for (int i=0;i<8;i++) {
      const float v = ls[co*289 + cic_l*72 + i*9 + tap] * 64.f;
      const _Float16 hi = (_Float16)v;
      hv[i] = hi;
      lv[i] = (_Float16)((v - (float)hi)*1024.f);
    }
    wbuf[(size_t)(((kt*9 + tap)*2 + 0)*4 + kg)*512 + co0 + co] = hv;
    wbuf[(size_t)(((kt*9 + tap)*2 + 1)*4 + kg)*512 + co0 + co] = lv;
  }
}

// ---------------- K1: 3x3 conv, 2-wave blocks, co_t=4, double-buffered (proven 271us) ----------------
// block 128 thr (2 waves); tile 128co x 48px; grid (2,96,4)=768 = 3 blocks/CU.
__global__ __launch_bounds__(128, 2) void rpn_conv_mfma(
    const f16x8* __restrict__ img, const f16x8* __restrict__ wbuf,
    const float* __restrict__ bias, float* __restrict__ out)
{
  __shared__ f16x8 in_s[2560];   // 2 buffers x 1280 slots x 16B
  const int tid = threadIdx.x;
  const int lane = tid & 63;
  const int wv = tid >> 6;        // 0..1
  const int kgrp = lane >> 4;
  const int ln15 = lane & 15;
  const int x0 = blockIdx.x * 48;
  const int y  = blockIdx.y;
  const int co0 = blockIdx.z * 128 + wv * 64;

  int goff[10];
#pragma unroll
  for (int j=0;j<10;j++) {
    int s = j*128 + tid; if (s > 1199) s = 1199;
    const int row = s / 400;
    const int rem = s - row*400;
    goff[j] = ((y + row)*98 + x0 + (rem>>3))*8 + (rem & 7);
  }
  const int ldst0 = wv*64;

  int keyb[3];
#pragma unroll
  for (int pt=0; pt<3; ++pt) keyb[pt] = x0 + pt*16 + ln15 + 1 + 2*y;

  f32x4 acc1[4][3], acc2[4][3];
#pragma unroll
  for (int c=0;c<4;c++)
#pragma unroll
    for (int pt=0;pt<3;pt++) {
      acc1[c][pt] = (f32x4){0.f,0.f,0.f,0.f};
      acc2[c][pt] = (f32x4){0.f,0.f,0.f,0.f};
    }

  const int wlane = kgrp*512 + co0 + ln15;

  // prologue: stage kt=0 into buffer 0
#pragma unroll
  for (int j=0;j<10;j++) gl_lds16(img + goff[j], in_s + j*128 + ldst0);
  asm volatile("s_waitcnt vmcnt(0)" ::: "memory");
  __syncthreads();

  for (int kt = 0; kt < 32; ++kt) {
    const int cur = (kt & 1) * 1280;
    if (kt < 31) {
      const f16x8* kb = img + (size_t)(kt+1)*76832;
#pragma unroll
      for (int j=0;j<10;j++) gl_lds16(kb + goff[j], in_s + (1280 - cur) + j*128 + ldst0);
    }
    const f16x8* bs = in_s + cur;
#pragma unroll
    for (int t=0; t<9; ++t) {
      const int dy = t/3 - 1, dx = t%3 - 1;
      f16x8 af[4][2];
#pragma unroll
      for (int h=0;h<2;h++) {
        const size_t wb = (size_t)(((kt*9 + t)*2 + h)*2048) + wlane;
#pragma unroll
        for (int c=0;c<4;c++) af[c][h] = wbuf[wb + c*16];
      }
      f16x8 bf[3][2];
#pragma unroll
      for (int pt=0;pt<3;pt++) {
        const int key = (keyb[pt] + dx + 2*dy) & 7;
        const int base = ((dy+1)*50 + pt*16 + ln15 + dx + 1)*8;
#pragma unroll
        for (int h=0;h<2;h++)
          bf[pt][h] = bs[base + ((h*4 + kgrp) ^ key)];
      }
#pragma unroll
      for (int c=0;c<4;c++)
#pragma unroll
        for (int pt=0;pt<3;pt++) {
          acc1[c][pt] = __builtin_amdgcn_mfma_f32_16x16x32_f16(af[c][0], bf[pt][0], acc1[c][pt], 0,0,0);
          acc2[c][pt] = __builtin_amdgcn_mfma_f32_16x16x32_f16(af[c][0], bf[pt][1], acc2[c][pt], 0,0,0);
          acc2[c][pt] = __builtin_amdgcn_mfma_f32_16x16x32_f16(af[c][1], bf[pt][0], acc2[c][pt], 0,0,0);
        }
    }
    asm volatile("s_waitcnt vmcnt(0)" ::: "memory");
    __syncthreads();
  }

  const int pixb = y*96 + x0;
#pragma unroll
  for (int c=0;c<4;c++) {
#pragma unroll
    for (int i=0;i<4;i++) {
      const int co = co0 + c*16 + kgrp*4 + i;
      const float bb = bias[co];
#pragma unroll
      for (int pt=0;pt<3;pt++) {
        const float v = (acc1[c][pt][i] + acc2[c][pt][i]*(1.f/1024.f))*(1.f/64.f) + bb;
        out[(size_t)co*HW + pixb + pt*16 + ln15] = v > 0.f ? v : 0.f;
      }
    }
  }
}

// ---------------- K2: 1x1 convs — 8-way ci-split partials + deterministic reduce ----------------
__global__ void conv1x1p(const float* __restrict__ rpn,
    const float* __restrict__ cw, const float* __restrict__ bw,
    float* __restrict__ partial)
{
  const int hw = blockIdx.x * 256 + threadIdx.x;
  const int cg = blockIdx.y;           // 0..7
  const int ci0 = cg * 64;
  float accA[18], accB[36];
#pragma unroll
  for (int c=0;c<18;c++) accA[c]=0.f;
#pragma unroll
  for (int c=0;c<36;c++) accB[c]=0.f;
  for (int ci=ci0; ci<ci0+64; ++ci) {
    const float v = rpn[(size_t)ci*HW + hw];
#pragma unroll
    for (int c=0;c<18;c++) accA[c] = fmaf(v, cw[c*CMID+ci], accA[c]);
#pragma unroll
    for (int c=0;c<36;c++) accB[c] = fmaf(v, bw[c*CMID+ci], accB[c]);
  }
  float* p = partial + (size_t)cg*54*HW;
#pragma unroll
  for (int c=0;c<18;c++) p[(size_t)c*HW + hw] = accA[c];
#pragma unroll
  for (int c=0;c<36;c++) p[(size_t)(18+c)*HW + hw] = accB[c];
}

__global__ void conv1x1r(const float* __restrict__ partial,
    const float* __restrict__ cb, const float* __restrict__ bb,
    float* __restrict__ cls_out, float* __restrict__ bbox_out)
{
  const int o = blockIdx.x*256 + threadIdx.x;    // 54*HW total
  const int c = o / HW;
  const int hw = o - c*HW;
  float v = partial[o];
#pragma unroll
  for (int g=1; g<8; ++g) v += partial[(size_t)g*54*HW + o];
  if (c < 18) cls_out[(size_t)c*HW + hw] = v + cb[c];
  else        bbox_out[(size_t)(c-18)*HW + hw] = v + bb[c-18];
}

// ---------------- K3: scores+keys+hist + decode+clip + anchor_ov + last-block hist scan ----------------
__global__ void score_decode_ov(const float* __restrict__ cls_out,
    const float* __restrict__ bbox_out, const float* __restrict__ im_info,
    const float* __restrict__ gt,
    u64* __restrict__ keys, float4* __restrict__ props, u32* __restrict__ hist10,
    float* __restrict__ ov, u32* __restrict__ gtmax,
    u32* __restrict__ done, u32* __restrict__ meta)
{
#pragma clang fp contract(off)
  __shared__ u32 h[1024];
  __shared__ u32 lmax[8];
  __shared__ int lastFlag;
  const int tid = threadIdx.x;
  for (int i=tid;i<1024;i+=256) h[i]=0;
  if (tid < 8) lmax[tid] = 0u;
  __syncthreads();
  const int n = blockIdx.x*256 + tid;
  const int hw = n / 9;
  const int a  = n - hw*9;
  const int x = hw % HF, y = hw / HF;
  const float l0 = cls_out[a*HW + hw];
  const float l1 = cls_out[(9+a)*HW + hw];
  const float m = fmaxf(l0, l1);
  const float e0 = expf(l0 - m), e1 = expf(l1 - m);
  const float s = e1 / (e0 + e1);
  const u32 sb = __float_as_uint(s);      // s >= 0 -> bits monotone
  keys[n] = ((u64)(~sb) << 32) | (u32)n;  // asc key == desc score, tie -> asc idx
  atomicAdd(&h[sb >> 22], 1u);

  const float ax1 = BA[a][0] + 16.f*(float)x;
  const float ay1 = BA[a][1] + 16.f*(float)y;
  const float ax2 = BA[a][2] + 16.f*(float)x;
  const float ay2 = BA[a][3] + 16.f*(float)y;
  const float aw = ax2 - ax1 + 1.f, ah = ay2 - ay1 + 1.f;
  const float cx = ax1 + 0.5f*aw,  cy = ay1 + 0.5f*ah;
  const float d0 = bbox_out[(a*4+0)*HW + hw];
  const float d1 = bbox_out[(a*4+1)*HW + hw];
  const float d2 = bbox_out[(a*4+2)*HW + hw];
  const float d3 = bbox_out[(a*4+3)*HW + hw];
  const float pcx = d0*aw + cx, pcy = d1*ah + cy;
  const float pw = expf(d2)*aw, ph = expf(d3)*ah;
  const float imh = im_info[0], imw = im_info[1];
  float bx1 = fminf(fmaxf(pcx - 0.5f*pw, 0.f), imw - 1.f);
  float by1 = fminf(fmaxf(pcy - 0.5f*ph, 0.f), imh - 1.f);
  float bx2 = fminf(fmaxf(pcx + 0.5f*pw, 0.f), imw - 1.f);
  float by2 = fminf(fmaxf(pcy + 0.5f*ph, 0.f), imh - 1.f);
  props[n] = make_float4(bx1, by1, bx2, by2);

  const bool inside = (ax1 >= 0.f) && (ay1 >= 0.f) && (ax2 < imw) && (ay2 < imh);
  const float aa = aw * ah;
#pragma unroll
  for (int j=0;j<8;j++) {
    const float g0=gt[j*5+0], g1=gt[j*5+1], g2=gt[j*5+2], g3=gt[j*5+3];
    const float ga = (g2-g0+1.f)*(g3-g1+1.f);
    const float xx1 = fmaxf(ax1,g0), yy1 = fmaxf(ay1,g1);
    const float xx2 = fminf(ax2,g2), yy2 = fminf(ay2,g3);
    const float inter = fmaxf(xx2-xx1+1.f,0.f)*fmaxf(yy2-yy1+1.f,0.f);
    const float iou = inter/(aa+ga-inter);
    const float o = inside ? iou : -1.f;
    ov[(size_t)n*8+j] = o;
    atomicMax(&lmax[j], fkey(o));
  }
  __syncthreads();
  for (int i=tid;i<1024;i+=256) if (h[i]) atomicAdd(&hist10[i], h[i]);
  if (tid < 8) atomicMax(&gtmax[tid], lmax[tid]);

  // last-block coarse hist scan (replaces hist_scan1 launch). hist10 updates are
  // device-scope atomics; threadfence orders this block's own updates; the block
  // whose counter increment is last observes all NBLK blocks' atomics complete.
  __threadfence();
  if (tid == 0) lastFlag = (atomicAdd(done, 1u) == (u32)(NBLK - 1)) ? 1 : 0;
  __syncthreads();
  if (lastFlag) {
    for (int i=tid;i<1024;i+=256) h[i] = hist10[i];
    __syncthreads();
    if (tid == 0) {
      u32 cum = 0;
      int b = 1023;
      for (; b > 0; --b) {
        if (cum + h[b] >= PRE) break;
        cum += h[b];
      }
      meta[0] = (u32)b;
      meta[1] = cum;
    }
  }
}

// ---------------- K4b: refine hist + anchor labels (fused) ----------------
__global__ void refine_label(const u64* __restrict__ keys, const u32* __restrict__ meta,
                             u32* __restrict__ h64,
                             const float* __restrict__ ov, const u32* __restrict__ gtmax,
                             signed char* __restrict__ labels, signed char* __restrict__ amax,
                             int* __restrict__ exP)
{
  __shared__ u32 h[64];
  __shared__ int se[256];
  const int tid = threadIdx.x;
  if (tid < 64) h[tid] = 0;
  __syncthreads();
  const int n = blockIdx.x*256 + tid;
  const u32 sb = ~(u32)(keys[n] >> 32);
  if ((sb >> 22) == meta[0]) atomicAdd(&h[(sb >> 16) & 63], 1u);

  float best = -3.402823466e38f;
  int arg = 0;
  bool isbest = false;
#pragma unroll
  for (int j=0;j<8;j++) {
    const float o = ov[(size_t)n*8+j];
    if (o > best) { best = o; arg = j; }
    if (fkey(o) == gtmax[j]) isbest = true;
  }
  const bool inside = ov[(size_t)n*8+0] >= 0.f;
  int lab = -1;
  if (inside && best < 0.3f) lab = 0;
  if (inside && isbest) lab = 1;
  if (inside && best >= 0.7f) lab = 1;
  labels[n] = (signed char)lab;
  amax[n] = (signed char)arg;
  se[tid] = (lab >= 0) ? 1 : 0;
  __syncthreads();
  if (tid < 64 && h[tid]) atomicAdd(&h64[tid], h[tid]);
  for (int s=128; s>0; s>>=1) {
    if (tid < s) se[tid] += se[tid+s];
    __syncthreads();
  }
  if (tid==0) exP[blockIdx.x] = se[0];
}

// ---------------- K5: threshold recompute + compact + loss partials (fused) ----------------
__global__ void collect_loss(const u64* __restrict__ keys,
                             const u32* __restrict__ meta, const u32* __restrict__ h64,
                             u32* __restrict__ counter, u64* __restrict__ cand,
                             const float* __restrict__ cls_out, const float* __restrict__ bbox_out,
                             const float* __restrict__ gt, const signed char* __restrict__ labels,
                             const signed char* __restrict__ amax, float2* __restrict__ lossP)
{
#pragma clang fp contract(off)
  __shared__ float sce[256];
  __shared__ float sbx[256];
  __shared__ u32 sthr;
  const int tid = threadIdx.x;
  if (tid == 0) {
    u32 cum = meta[1];
    int s = 63;
    for (; s > 0; --s) { cum += h64[s]; if (cum >= PRE) break; }
    sthr = (meta[0] << 6) | (u32)s;
  }
  __syncthreads();
  const u32 thr = sthr;
  const int n = blockIdx.x*256 + tid;
  const u64 k = keys[n];
  const u32 sb = ~(u32)(k >> 32);
  if ((sb >> 16) >= thr) {
    u32 p = atomicAdd(counter, 1u);
    cand[p] = k;
  }
  const int hw = n/9, a = n - hw*9;
  const int lab = labels[n];
  float ce = 0.f, bx = 0.f;
  if (lab >= 0) {
    const float l0 = cls_out[a*HW+hw], l1 = cls_out[(9+a)*HW+hw];
    const float m = fmaxf(l0,l1);
    const float lse = m + logf(expf(l0-m)+expf(l1-m));
    ce = lse - (lab==1 ? l1 : l0);
  }
  if (lab == 1) {
    const int x = hw % HF, y = hw / HF;
    const float ax1 = BA[a][0]+16.f*(float)x, ay1 = BA[a][1]+16.f*(float)y;
    const float ax2 = BA[a][2]+16.f*(float)x, ay2 = BA[a][3]+16.f*(float)y;
    const float ew = ax2-ax1+1.f, eh = ay2-ay1+1.f;
    const float ecx = ax1+0.5f*ew, ecy = ay1+0.5f*eh;
    const int g = amax[n];
    const float g0=gt[g*5+0], g1=gt[g*5+1], g2=gt[g*5+2], g3=gt[g*5+3];
    const float gw = g2-g0+1.f, gh = g3-g1+1.f;
    const float gcx = g0+0.5f*gw, gcy = g1+0.5f*gh;
    float tgt[4];
    tgt[0] = (gcx-ecx)/ew;
    tgt[1] = (gcy-ecy)/eh;
    tgt[2] = logf(gw/ew);
    tgt[3] = logf(gh/eh);
#pragma unroll
    for (int j=0;j<4;j++) {
      const float d = bbox_out[(a*4+j)*HW+hw];
      const float diff = d - tgt[j];
      const float ad = fabsf(diff);
      bx += (ad < (1.0f/9.0f)) ? (4.5f*diff*diff) : (ad - 0.5f/9.0f);
    }
  }
  sce[tid]=ce; sbx[tid]=bx;
  __syncthreads();
  for (int s=128;s>0;s>>=1) {
    if (tid<s) { sce[tid]+=sce[tid+s]; sbx[tid]+=sbx[tid+s]; }
    __syncthreads();
  }
  if (tid==0) lossP[blockIdx.x] = make_float2(sce[0], sbx[0]);
}

// ---------------- K6a: partial ranks (j-parallel) ----------------
__global__ void rank_partial(const u64* __restrict__ cand, const u32* __restrict__ counter,
                             u32* __restrict__ rankbuf)
{
  __shared__ u64 sk[256];
  const int M = (int)counter[0];
  if (blockIdx.x*256 >= M) return;
  const int i = blockIdx.x*256 + threadIdx.x;
  const u64 key = (i < M) ? cand[i] : ~0ull;
  const int chunk = ((M + 7)/8 + 255) & ~255;
  const int j0 = blockIdx.y*chunk;
  const int j1 = (j0 + chunk < M) ? (j0 + chunk) : M;
  int rank = 0;
  for (int t0 = j0; t0 < j1; t0 += 256) {
    const int j = t0 + threadIdx.x;
    sk[threadIdx.x] = (j < M) ? cand[j] : ~0ull;
    __syncthreads();
    const int lim = (j1 - t0 < 256) ? (j1 - t0) : 256;
    for (int k=0;k<lim;k++) rank += (sk[k] < key) ? 1 : 0;
    __syncthreads();
  }
  if (i < M && rank) atomicAdd(&rankbuf[i], (u32)rank);
}

// ---------------- K6b: scatter by rank ----------------
__global__ void rank_scatter2(const u64* __restrict__ cand, const u32* __restrict__ counter,
                              const u32* __restrict__ rankbuf, const float4* __restrict__ props,
                              float4* __restrict__ sprops)
{
  const int M = (int)counter[0];
  const int i = blockIdx.x*256 + threadIdx.x;
  if (i >= M) return;
  const u32 r = rankbuf[i];
  if (r < PRE) sprops[r] = props[(u32)cand[i]];
}

// ---------------- K7: NMS suppression bitmask (256-thr blocks, upper triangle) ----------------
__global__ void nms_mask(const float4* __restrict__ sp, u64* __restrict__ mask)
{
#pragma clang fp contract(off)
  const int c0 = blockIdx.x * 64;
  const int r0 = blockIdx.y * 256;
  if (c0 + 63 < r0) return;
  __shared__ float4 cb[64];
  __shared__ float  ca[64];
  const int tid = threadIdx.x;
  const int cend = min(64, PRE - c0);
  if (tid < cend) {
    float4 b = sp[c0 + tid];
    cb[tid] = b;
    ca[tid] = (b.z-b.x+1.f)*(b.w-b.y+1.f);
  }
  __syncthreads();
  const int row = r0 + tid;
  if (row >= PRE) return;
  const float4 rb = sp[row];
  const float ra = (rb.z-rb.x+1.f)*(rb.w-rb.y+1.f);
  u64 bits = 0;
  for (int j=0;j<cend;j++) {
    const float4 c = cb[j];
    const float xx1 = fmaxf(rb.x, c.x), yy1 = fmaxf(rb.y, c.y);
    const float xx2 = fminf(rb.z, c.z), yy2 = fminf(rb.w, c.w);
    const float inter = fmaxf(xx2-xx1+1.f, 0.f) * fmaxf(yy2-yy1+1.f, 0.f);
    const float iou = inter / (ra + ca[j] - inter);
    if (iou > 0.7f) bits |= (1ull << j);
  }
  mask[(size_t)row*NW + blockIdx.x] = bits;
}

// ---------------- K8: fused {chunked NMS scan | loss_final | feat transpose} ----------------
__global__ void fused_scan_tr(const u64* __restrict__ mask, const float4* __restrict__ sp,
                              float* __restrict__ rois,
                              const float2* __restrict__ lossP, const int* __restrict__ exP,
                              float* __restrict__ out,
                              const float* __restrict__ feat, float* __restrict__ featT, int doT)
{
  const int b = blockIdx.x;
  if (b == 0) {
    __shared__ u64 mslice[4096];     // 512 rows x 8 words (32 KB)
    __shared__ u64 vbits[8];
    __shared__ int keep_s[POST];
    __shared__ int s_nsel;
    const int tid = threadIdx.x;
    for (int i = tid; i < POST; i += 256) keep_s[i] = 0;
    if (tid == 0) s_nsel = 0;
    __syncthreads();
    for (int c = 0; c < 24; ++c) {
      if (s_nsel >= POST) break;                 // uniform (post-barrier value)
      const int base = c * 512;
      const int cnt = (PRE - base < 512) ? (PRE - base) : 512;   // 512 or 224
      if (tid < 8) {
        u64 v = 0;
        const int lo = tid * 64;
        if (lo < cnt) {
          v = ~0ull;
          const int rem = cnt - lo;
          if (rem < 64) v = (1ull << rem) - 1ull;
        }
        vbits[tid] = v;
      }
      __syncthreads();
      for (int k = tid; k < cnt*8; k += 256) {
        const int i = k >> 3, w = k & 7;
        mslice[k] = mask[(size_t)(base + i)*NW + c*8 + w];
      }
      const int ns = s_nsel;
      for (int k = tid; k < ns*8; k += 256) {
        const int s = k >> 3, w = k & 7;
        const u64 row = mask[(size_t)keep_s[s]*NW + c*8 + w];
        if (row) atomicAnd(&vbits[w], ~row);
      }
      __syncthreads();
      if (tid < 64) {
        const int l = tid;
        u64 v = (l < 8) ? vbits[l] : 0;
        int nsel = s_nsel;
        for (;;) {
          const u64 bal = __ballot(v != 0);
          if (bal == 0) break;
          const int src = __ffsll((unsigned long long)bal) - 1;
          int fi = 0;
          if (v) fi = l*64 + __ffsll(v) - 1;
          const int il = __shfl(fi, src);
          if (l == 0) keep_s[nsel] = base + il;
          nsel++;
          if (nsel >= POST) break;
          if (l < 8) v &= ~mslice[(il << 3) | l];
        }
        if (l == 0) s_nsel = nsel;
      }
      __syncthreads();
    }
    for (int i = tid; i < POST; i += 256) {
      const float4 bb = sp[keep_s[i]];
      rois[i*5+0] = 0.f;
      rois[i*5+1] = bb.x; rois[i*5+2] = bb.y; rois[i*5+3] = bb.z; rois[i*5+4] = bb.w;
    }
  } else if (b == 1) {
    __shared__ float a[256];
    __shared__ float c[256];
    __shared__ int   e[256];
    const int t = threadIdx.x;
    float ax = 0.f, cx = 0.f; int ev = 0;
    if (t < NBLK) { float2 v = lossP[t]; ax = v.x; cx = v.y; ev = exP[t]; }
    if (t + 256 < NBLK) { float2 v = lossP[t+256]; ax += v.x; cx += v.y; ev += exP[t+256]; }
    a[t]=ax; c[t]=cx; e[t]=ev;
    __syncthreads();
    for (int s=128;s>0;s>>=1) {
      if (t<s) { a[t]+=a[t+s]; c[t]+=c[t+s]; e[t]+=e[t+s]; }
      __syncthreads();
    }
    if (t==0) {
      const float nex = (float)max(e[0], 1);
      out[OUT_POOL+0] = a[0] / nex;
      out[OUT_POOL+1] = c[0] / nex;
    }
  } else if (doT) {
    __shared__ float t[64][65];
    const int tt = b - 2;               // 0..2303
    const int bxhw = (tt % 144)*64, byc = (tt / 144)*64;
    const int tid = threadIdx.x;
    const int l = tid & 63, g = tid >> 6;
#pragma unroll
    for (int i=0;i<16;i++) {
      const int cL = g + 4*i;
      t[cL][l] = feat[(size_t)(byc+cL)*HW + bxhw + l];
    }
    __syncthreads();
#pragma unroll
    for (int i=0;i<16;i++) {
      const int hwL = g + 4*i;
      featT[(size_t)(bxhw+hwL)*1024 + byc + l] = t[l][hwL];
    }
  }
}

// ---------------- K9: ROI bilinear crop ----------------
struct __align__(16) Samp { int p0,p1,p2,p3; float w0,w1,w2,w3; };

__device__ __forceinline__ Samp make_samp(const float* __restrict__ rois, int r, int s)
{
#pragma clang fp contract(off)
  const int py = s / 7, px = s - py*7;
  const float x1 = rois[r*5+1] * 0.0625f;
  const float y1 = rois[r*5+2] * 0.0625f;
  const float x2 = rois[r*5+3] * 0.0625f;
  const float y2 = rois[r*5+4] * 0.0625f;
  const float t00 = (x2-x1)/95.f;
  const float t02 = (x1+x2-95.f)/95.f;
  const float t11 = (y2-y1)/95.f;
  const float t12 = (y1+y2-95.f)/95.f;
  const float lx = (float)(px-3)/3.f;
  const float ly = (float)(py-3)/3.f;
  const float gx = t00*lx + t02;
  const float gy = t11*ly + t12;
  const float ix = (gx+1.f)*0.5f*95.f;
  const float iy = (gy+1.f)*0.5f*95.f;
  const float ix0 = floorf(ix), iy0 = floorf(iy);
  const float wx = ix-ix0, wy = iy-iy0;
  const float xs[2] = {ix0, ix0+1.f};
  const float ys[2] = {iy0, iy0+1.f};
  const float wxs[2] = {1.f-wx, wx};
  const float wys[2] = {1.f-wy, wy};
  int pos[4]; float wt[4];
#pragma unroll
  for (int k=0;k<4;k++) {
    const int dy = k>>1, dx = k&1;
    const float yi = ys[dy], xi = xs[dx];
    const bool valid = (yi>=0.f)&&(yi<96.f)&&(xi>=0.f)&&(xi<96.f);
    const int yc = (int)fminf(fmaxf(yi,0.f),95.f);
    const int xc = (int)fminf(fmaxf(xi,0.f),95.f);
    pos[k] = yc*96+xc;
    wt[k] = wys[dy]*wxs[dx] * (valid?1.f:0.f);
  }
  Samp t;
  t.p0=pos[0]; t.p1=pos[1]; t.p2=pos[2]; t.p3=pos[3];
  t.w0=wt[0];  t.w1=wt[1];  t.w2=wt[2];  t.w3=wt[3];
  return t;
}

__global__ void roi_pool_coal(const float* __restrict__ featT, const float* __restrict__ rois,
                              float* __restrict__ out)
{
#pragma clang fp contract(off)
  __shared__ float st[49][257];
  __shared__ Samp sam[49];
  const int tid = threadIdx.x;
  const int r = blockIdx.x, cb = blockIdx.y;
  if (tid < 49) sam[tid] = make_samp(rois, r, tid);
  __syncthreads();
  const int c = cb*256 + tid;
  for (int s=0;s<49;s++) {
    const Samp t = sam[s];
    st[s][tid] = t.w0*featT[(size_t)t.p0*1024+c] + t.w1*featT[(size_t)t.p1*1024+c]
               + t.w2*featT[(size_t)t.p2*1024+c] + t.w3*featT[(size_t)t.p3*1024+c];
  }
  __syncthreads();
  float* ob = out + (size_t)r*50176 + cb*12544;
  for (int i=tid; i<12544; i+=256) {
    const int cL = i / 49, s = i - cL*49;
    ob[i] = st[s][cL];
  }
}

__global__ void roi_pool_gather(const float* __restrict__ feat, const float* __restrict__ rois,
                                float* __restrict__ out)
{
#pragma clang fp contract(off)
  const int o = blockIdx.x*256 + threadIdx.x;
  const int s  = o % 49;
  const int rc = o / 49;
  const int c = rc & (CIN-1);
  const int r = rc >> 10;
  const Samp t = make_samp(rois, r, s);
  const float* f = feat + (size_t)c*HW;
  out[o] = t.w0*f[t.p0] + t.w1*f[t.p1] + t.w2*f[t.p2] + t.w3*f[t.p3];
}

// ---------------- launcher ----------------
extern "C" void kernel_launch(void* const* d_in, const int* in_sizes, int n_in,
                              void* d_out, int out_size, void* d_ws, size_t ws_size,
                              hipStream_t stream)
{
  const float* feat    = (const float*)d_in[0];
  const float* gt      = (const float*)d_in[1];
  const float* im_info = (const float*)d_in[2];
  const float* rpn_w   = (const float*)d_in[3];
  const float* rpn_b   = (const float*)d_in[4];
  const float* cls_w   = (const float*)d_in[5];
  const float* cls_b   = (const float*)d_in[6];
  const float* bbox_w  = (const float*)d_in[7];
  const float* bbox_b  = (const float*)d_in[8];
  float* out = (float*)d_out;
  char* ws = (char*)d_ws;

  size_t off = 0;
  auto alloc = [&](size_t bytes) {
    size_t o = off;
    off = (off + bytes + 255) & ~(size_t)255;
    return o;
  };
  // zero-region (memset every call)
  size_t o_counter = alloc(4);
  size_t o_done    = alloc(4);
  size_t o_gtmax   = alloc(32);
  size_t o_meta    = alloc(8);
  size_t o_h64     = alloc(256);
  size_t o_hist10  = alloc(1024*4);
  size_t o_rank    = alloc((size_t)NA*4);
  size_t zeroBytes = off;
  // persistent across phases
  size_t o_cls  = alloc((size_t)18*HW*4);
  size_t o_bbox = alloc((size_t)36*HW*4);
  size_t o_rpn  = alloc((size_t)CMID*HW*4);
  // overlapped region R
  size_t o_R = off;
  const size_t IMG_BYTES  = (size_t)32*98*98*8*16;   // 39,337,984
  const size_t WBUF_BYTES = (size_t)9*2*128*512*16;  // 18,874,368
  const size_t FEATT_BYTES= (size_t)HW*1024*4;       // 37,748,736
  size_t o_img  = o_R;
  size_t o_wbuf = o_R + ((IMG_BYTES + 255) & ~(size_t)255);
  size_t baseC_A = o_R + ((FEATT_BYTES + 255) & ~(size_t)255);
  auto phaseC = [&](size_t base, size_t* offs) {
    size_t co = base;
    auto ca = [&](size_t bytes) { size_t o = co; co = (co + bytes + 255) & ~(size_t)255; return o; };
    offs[0] = ca((size_t)8*54*HW*4);          // partial (phase B)
    co = base;                                // phase C overlays partial
    offs[1] = ca((size_t)NA*8);               // keys
    offs[2] = ca((size_t)NA*16);              // props
    offs[3] = ca((size_t)NA*8);               // cand
    offs[4] = ca((size_t)PRE*16);             // sprops
    offs[5] = ca((size_t)PRE*NW*8);           // mask
    offs[6] = ca((size_t)POST*5*4);           // rois
    offs[7] = ca((size_t)NA*8*4);             // ov
    offs[8] = ca((size_t)NA);                 // labels
    offs[9] = ca((size_t)NA);                 // amax
    offs[10]= ca((size_t)NBLK*4);             // exP
    offs[11]= ca((size_t)NBLK*8);             // lossP
    size_t endC = co;
    size_t endB = base + (size_t)8*54*HW*4;
    return endC > endB ? endC : endB;
  };
  size_t offsA[12], offsB[12];
  size_t endA = phaseC(baseC_A, offsA);
  size_t convEnd = o_wbuf + WBUF_BYTES;
  size_t neededA = (endA > convEnd ? endA : convEnd);
  size_t endB = phaseC(o_R, offsB);
  (void)endB;
  const bool useT = (ws_size >= neededA);
  const size_t* offs = useT ? offsA : offsB;
  (void)in_sizes; (void)n_in; (void)out_size;

  hipMemsetAsync(ws, 0, zeroBytes, stream);

  f16x8* img      = (f16x8*)(ws + o_img);
  f16x8* wbuf     = (f16x8*)(ws + o_wbuf);
  float* featT    = (float*)(ws + o_R);
  float* partial  = (float*)(ws + offs[0]);
  float* rpn      = (float*)(ws + o_rpn);
  float* cls_out  = (float*)(ws + o_cls);
  float* bbox_out = (float*)(ws + o_bbox);
  u64*   keys     = (u64*)(ws + offs[1]);
  float4* props   = (float4*)(ws + offs[2]);
  u64*   cand     = (u64*)(ws + offs[3]);
  float4* sprops  = (float4*)(ws + offs[4]);
  u64*   maskp    = (u64*)(ws + offs[5]);
  float* rois     = (float*)(ws + offs[6]);
  float* ovp      = (float*)(ws + offs[7]);
  signed char* labels = (signed char*)(ws + offs[8]);
  signed char* amax   = (signed char*)(ws + offs[9]);
  int*    exP     = (int*)(ws + offs[10]);
  float2* lossP   = (float2*)(ws + offs[11]);
  u32* counter    = (u32*)(ws + o_counter);
  u32* donep      = (u32*)(ws + o_done);
  u32* gtmaxp     = (u32*)(ws + o_gtmax);
  u32* metap      = (u32*)(ws + o_meta);
  u32* h64p       = (u32*)(ws + o_h64);
  u32* hist10     = (u32*)(ws + o_hist10);
  u32* rankbuf    = (u32*)(ws + o_rank);

  // phase A: conv via split-fp16 MFMA
  prep_img<<<dim3(98,32), 256, 0, stream>>>(feat, img);
  prep_w<<<dim3(8,32), 256, 0, stream>>>(rpn_w, wbuf);
  rpn_conv_mfma<<<dim3(2,96,4), 128, 0, stream>>>(img, wbuf, rpn_b, rpn);
  // phase B: 1x1 convs
  conv1x1p<<<dim3(36,8), 256, 0, stream>>>(rpn, cls_w, bbox_w, partial);
  conv1x1r<<<54*HW/256, 256, 0, stream>>>(partial, cls_b, bbox_b, cls_out, bbox_out);
  // phase C: proposals + anchor targets (hist scan fused via last-block)
  score_decode_ov<<<NBLK, 256, 0, stream>>>(cls_out, bbox_out, im_info, gt,
                                            keys, props, hist10, ovp, gtmaxp,
                                            donep, metap);
  refine_label<<<NBLK, 256, 0, stream>>>(keys, metap, h64p, ovp, gtmaxp, labels, amax, exP);
  collect_loss<<<NBLK, 256, 0, stream>>>(keys, metap, h64p, counter, cand,
                                         cls_out, bbox_out, gt, labels, amax, lossP);
  rank_partial<<<dim3(NBLK,8), 256, 0, stream>>>(cand, counter, rankbuf);
  rank_scatter2<<<NBLK, 256, 0, stream>>>(cand, counter, rankbuf, props, sprops);
  nms_mask<<<dim3(NW, 47), 256, 0, stream>>>(sprops, maskp);
  fused_scan_tr<<<2306, 256, 0, stream>>>(maskp, sprops, rois, lossP, exP, out,
                                          feat, featT, useT ? 1 : 0);
  if (useT) roi_pool_coal<<<dim3(POST,4), 256, 0, stream>>>(featT, rois, out);
  else      roi_pool_gather<<<OUT_POOL/256, 256, 0, stream>>>(feat, rois, out);
}

// Round 14
// 607.260 us; speedup vs baseline: 1.0319x; 1.0319x over previous
//
#include <hip/hip_runtime.h>
#include <stdint.h>

typedef unsigned int u32;
typedef unsigned long long u64;
typedef _Float16 f16x8 __attribute__((ext_vector_type(8)));
typedef float f32x4 __attribute__((ext_vector_type(4)));

#define HF 96
#define HW 9216           // 96*96
#define CIN 1024
#define CMID 512
#define NA 82944          // HW*9
#define PRE 12000
#define POST 300
#define NW 188            // ceil(PRE/64)
#define NBLK 324          // NA/256
#define OUT_POOL (POST*CIN*49)

// base anchors, exact per np.round (banker's) of the reference generator
__device__ __constant__ float BA[9][4] = {
  {-84.f,-40.f,99.f,55.f}, {-176.f,-88.f,191.f,103.f}, {-360.f,-184.f,375.f,199.f},
  {-56.f,-56.f,71.f,71.f}, {-120.f,-120.f,135.f,135.f}, {-248.f,-248.f,263.f,263.f},
  {-36.f,-80.f,51.f,95.f}, {-80.f,-168.f,95.f,183.f},  {-168.f,-344.f,183.f,359.f}
};

__device__ __forceinline__ u32 fkey(float f) {
  u32 u = __float_as_uint(f);
  return (u & 0x80000000u) ? ~u : (u | 0x80000000u);
}

__device__ __forceinline__ void gl_lds16(const void* g, void* l) {
  __builtin_amdgcn_global_load_lds((const __attribute__((address_space(1))) void*)g,
                                   (__attribute__((address_space(3))) void*)l, 16, 0, 0);
}

// ---------------- P1: feat -> swizzled fp16 hi/lo image with halo (coalesced) ----------------
__global__ void prep_img(const float* __restrict__ feat, f16x8* __restrict__ img)
{
  __shared__ float ls[32][100];
  const int yy = blockIdx.x;
  const int kt = blockIdx.y;
  const int tid = threadIdx.x;
  const int y = yy - 1;
  const bool yok = (unsigned)y < 96u;
  if (yok) {
    for (int e = tid; e < 3072; e += 256) {
      const int ci = e / 96;
      const int x = e - ci * 96;
      ls[ci][x] = feat[(size_t)(kt*32 + ci)*HW + y*96 + x];
    }
  }
  __syncthreads();
  for (int idx = tid; idx < 784; idx += 256) {
    const int col = idx >> 3;
    const int q = idx & 7;
    const int x = col - 1;
    f16x8 val;
#pragma unroll
    for (int i=0;i<8;i++) val[i] = (_Float16)0.f;
    if (yok && (unsigned)x < 96u) {
#pragma unroll
      for (int i=0;i<8;i++) {
        const float v = ls[(q&3)*8 + i][x];
        if (q < 4) val[i] = (_Float16)v;
        else { const _Float16 hi = (_Float16)v; val[i] = (_Float16)((v - (float)hi)*1024.f); }
      }
    }
    const int sw = (col + 2*y) & 7;
    img[(size_t)((kt*98 + yy)*98 + col)*8 + (q ^ sw)] = val;
  }
}

// ---------------- P2: weights -> frag-ready hi/lo (x64 pre-scale), LDS-coalesced ----------------
__global__ void prep_w(const float* __restrict__ w, f16x8* __restrict__ wbuf)
{
  __shared__ float ls[64*289];
  const int co0 = blockIdx.x * 64;
  const int cic0 = blockIdx.y * 4;
  const int tid = threadIdx.x;
  for (int e = tid; e < 64*288; e += 256) {
    const int co = e / 288;
    const int off = e - co*288;
    ls[co*289 + off] = w[(size_t)(co0+co)*9216 + cic0*72 + off];
  }
  __syncthreads();
  const int co = tid & 63;
  for (int task = tid >> 6; task < 36; task += 4) {
    const int cic_l = task / 9;
    const int tap = task - cic_l*9;
    const int cic = cic0 + cic_l;
    const int kt = cic >> 2, kg = cic & 3;
    f16x8 hv, lv;
#pragma unroll
    for (int i=0;i<8;i++) {
      const float v = ls[co*289 + cic_l*72 + i*9 + tap] * 64.f;
      const _Float16 hi = (_Float16)v;
      hv[i] = hi;
      lv[i] = (_Float16)((v - (float)hi)*1024.f);
    }
    wbuf[(size_t)(((kt*9 + tap)*2 + 0)*4 + kg)*512 + co0 + co] = hv;
    wbuf[(size_t)(((kt*9 + tap)*2 + 1)*4 + kg)*512 + co0 + co] = lv;
  }
}

// ---------------- K1: 3x3 conv, 2-wave blocks, co_t=4, double-buffered (proven 271us) ----------------
// block 128 thr (2 waves); tile 128co x 48px; grid (2,96,4)=768 = 3 blocks/CU.
__global__ __launch_bounds__(128, 2) void rpn_conv_mfma(
    const f16x8* __restrict__ img, const f16x8* __restrict__ wbuf,
    const float* __restrict__ bias, float* __restrict__ out)
{
  __shared__ f16x8 in_s[2560];   // 2 buffers x 1280 slots x 16B
  const int tid = threadIdx.x;
  const int lane = tid & 63;
  const int wv = tid >> 6;        // 0..1
  const int kgrp = lane >> 4;
  const int ln15 = lane & 15;
  const int x0 = blockIdx.x * 48;
  const int y  = blockIdx.y;
  const int co0 = blockIdx.z * 128 + wv * 64;

  int goff[10];
#pragma unroll
  for (int j=0;j<10;j++) {
    int s = j*128 + tid; if (s > 1199) s = 1199;
    const int row = s / 400;
    const int rem = s - row*400;
    goff[j] = ((y + row)*98 + x0 + (rem>>3))*8 + (rem & 7);
  }
  const int ldst0 = wv*64;

  int keyb[3];
#pragma unroll
  for (int pt=0; pt<3; ++pt) keyb[pt] = x0 + pt*16 + ln15 + 1 + 2*y;

  f32x4 acc1[4][3], acc2[4][3];
#pragma unroll
  for (int c=0;c<4;c++)
#pragma unroll
    for (int pt=0;pt<3;pt++) {
      acc1[c][pt] = (f32x4){0.f,0.f,0.f,0.f};
      acc2[c][pt] = (f32x4){0.f,0.f,0.f,0.f};
    }

  const int wlane = kgrp*512 + co0 + ln15;

  // prologue: stage kt=0 into buffer 0
#pragma unroll
  for (int j=0;j<10;j++) gl_lds16(img + goff[j], in_s + j*128 + ldst0);
  asm volatile("s_waitcnt vmcnt(0)" ::: "memory");
  __syncthreads();

  for (int kt = 0; kt < 32; ++kt) {
    const int cur = (kt & 1) * 1280;
    if (kt < 31) {
      const f16x8* kb = img + (size_t)(kt+1)*76832;
#pragma unroll
      for (int j=0;j<10;j++) gl_lds16(kb + goff[j], in_s + (1280 - cur) + j*128 + ldst0);
    }
    const f16x8* bs = in_s + cur;
#pragma unroll
    for (int t=0; t<9; ++t) {
      const int dy = t/3 - 1, dx = t%3 - 1;
      f16x8 af[4][2];
#pragma unroll
      for (int h=0;h<2;h++) {
        const size_t wb = (size_t)(((kt*9 + t)*2 + h)*2048) + wlane;
#pragma unroll
        for (int c=0;c<4;c++) af[c][h] = wbuf[wb + c*16];
      }
      f16x8 bf[3][2];
#pragma unroll
      for (int pt=0;pt<3;pt++) {
        const int key = (keyb[pt] + dx + 2*dy) & 7;
        const int base = ((dy+1)*50 + pt*16 + ln15 + dx + 1)*8;
#pragma unroll
        for (int h=0;h<2;h++)
          bf[pt][h] = bs[base + ((h*4 + kgrp) ^ key)];
      }
#pragma unroll
      for (int c=0;c<4;c++)
#pragma unroll
        for (int pt=0;pt<3;pt++) {
          acc1[c][pt] = __builtin_amdgcn_mfma_f32_16x16x32_f16(af[c][0], bf[pt][0], acc1[c][pt], 0,0,0);
          acc2[c][pt] = __builtin_amdgcn_mfma_f32_16x16x32_f16(af[c][0], bf[pt][1], acc2[c][pt], 0,0,0);
          acc2[c][pt] = __builtin_amdgcn_mfma_f32_16x16x32_f16(af[c][1], bf[pt][0], acc2[c][pt], 0,0,0);
        }
    }
    asm volatile("s_waitcnt vmcnt(0)" ::: "memory");
    __syncthreads();
  }

  const int pixb = y*96 + x0;
#pragma unroll
  for (int c=0;c<4;c++) {
#pragma unroll
    for (int i=0;i<4;i++) {
      const int co = co0 + c*16 + kgrp*4 + i;
      const float bb = bias[co];
#pragma unroll
      for (int pt=0;pt<3;pt++) {
        const float v = (acc1[c][pt][i] + acc2[c][pt][i]*(1.f/1024.f))*(1.f/64.f) + bb;
        out[(size_t)co*HW + pixb + pt*16 + ln15] = v > 0.f ? v : 0.f;
      }
    }
  }
}

// ---------------- K2: 1x1 convs — 8-way ci-split partials + deterministic reduce ----------------
__global__ void conv1x1p(const float* __restrict__ rpn,
    const float* __restrict__ cw, const float* __restrict__ bw,
    float* __restrict__ partial)
{
  const int hw = blockIdx.x * 256 + threadIdx.x;
  const int cg = blockIdx.y;           // 0..7
  const int ci0 = cg * 64;
  float accA[18], accB[36];
#pragma unroll
  for (int c=0;c<18;c++) accA[c]=0.f;
#pragma unroll
  for (int c=0;c<36;c++) accB[c]=0.f;
  for (int ci=ci0; ci<ci0+64; ++ci) {
    const float v = rpn[(size_t)ci*HW + hw];
#pragma unroll
    for (int c=0;c<18;c++) accA[c] = fmaf(v, cw[c*CMID+ci], accA[c]);
#pragma unroll
    for (int c=0;c<36;c++) accB[c] = fmaf(v, bw[c*CMID+ci], accB[c]);
  }
  float* p = partial + (size_t)cg*54*HW;
#pragma unroll
  for (int c=0;c<18;c++) p[(size_t)c*HW + hw] = accA[c];
#pragma unroll
  for (int c=0;c<36;c++) p[(size_t)(18+c)*HW + hw] = accB[c];
}

__global__ void conv1x1r(const float* __restrict__ partial,
    const float* __restrict__ cb, const float* __restrict__ bb,
    float* __restrict__ cls_out, float* __restrict__ bbox_out)
{
  const int o = blockIdx.x*256 + threadIdx.x;    // 54*HW total
  const int c = o / HW;
  const int hw = o - c*HW;
  float v = partial[o];
#pragma unroll
  for (int g=1; g<8; ++g) v += partial[(size_t)g*54*HW + o];
  if (c < 18) cls_out[(size_t)c*HW + hw] = v + cb[c];
  else        bbox_out[(size_t)(c-18)*HW + hw] = v + bb[c-18];
}

// ---------------- K3: scores+keys+hist + decode+clip + anchor_ov (fused) ----------------
__global__ void score_decode_ov(const float* __restrict__ cls_out,
    const float* __restrict__ bbox_out, const float* __restrict__ im_info,
    const float* __restrict__ gt,
    u64* __restrict__ keys, float4* __restrict__ props, u32* __restrict__ hist10,
    float* __restrict__ ov, u32* __restrict__ gtmax)
{
#pragma clang fp contract(off)
  __shared__ u32 h[1024];
  __shared__ u32 lmax[8];
  const int tid = threadIdx.x;
  for (int i=tid;i<1024;i+=256) h[i]=0;
  if (tid < 8) lmax[tid] = 0u;
  __syncthreads();
  const int n = blockIdx.x*256 + tid;
  const int hw = n / 9;
  const int a  = n - hw*9;
  const int x = hw % HF, y = hw / HF;
  const float l0 = cls_out[a*HW + hw];
  const float l1 = cls_out[(9+a)*HW + hw];
  const float m = fmaxf(l0, l1);
  const float e0 = expf(l0 - m), e1 = expf(l1 - m);
  const float s = e1 / (e0 + e1);
  const u32 sb = __float_as_uint(s);      // s >= 0 -> bits monotone
  keys[n] = ((u64)(~sb) << 32) | (u32)n;  // asc key == desc score, tie -> asc idx
  atomicAdd(&h[sb >> 22], 1u);

  const float ax1 = BA[a][0] + 16.f*(float)x;
  const float ay1 = BA[a][1] + 16.f*(float)y;
  const float ax2 = BA[a][2] + 16.f*(float)x;
  const float ay2 = BA[a][3] + 16.f*(float)y;
  const float aw = ax2 - ax1 + 1.f, ah = ay2 - ay1 + 1.f;
  const float cx = ax1 + 0.5f*aw,  cy = ay1 + 0.5f*ah;
  const float d0 = bbox_out[(a*4+0)*HW + hw];
  const float d1 = bbox_out[(a*4+1)*HW + hw];
  const float d2 = bbox_out[(a*4+2)*HW + hw];
  const float d3 = bbox_out[(a*4+3)*HW + hw];
  const float pcx = d0*aw + cx, pcy = d1*ah + cy;
  const float pw = expf(d2)*aw, ph = expf(d3)*ah;
  const float imh = im_info[0], imw = im_info[1];
  float bx1 = fminf(fmaxf(pcx - 0.5f*pw, 0.f), imw - 1.f);
  float by1 = fminf(fmaxf(pcy - 0.5f*ph, 0.f), imh - 1.f);
  float bx2 = fminf(fmaxf(pcx + 0.5f*pw, 0.f), imw - 1.f);
  float by2 = fminf(fmaxf(pcy + 0.5f*ph, 0.f), imh - 1.f);
  props[n] = make_float4(bx1, by1, bx2, by2);

  const bool inside = (ax1 >= 0.f) && (ay1 >= 0.f) && (ax2 < imw) && (ay2 < imh);
  const float aa = aw * ah;
#pragma unroll
  for (int j=0;j<8;j++) {
    const float g0=gt[j*5+0], g1=gt[j*5+1], g2=gt[j*5+2], g3=gt[j*5+3];
    const float ga = (g2-g0+1.f)*(g3-g1+1.f);
    const float xx1 = fmaxf(ax1,g0), yy1 = fmaxf(ay1,g1);
    const float xx2 = fminf(ax2,g2), yy2 = fminf(ay2,g3);
    const float inter = fmaxf(xx2-xx1+1.f,0.f)*fmaxf(yy2-yy1+1.f,0.f);
    const float iou = inter/(aa+ga-inter);
    const float o = inside ? iou : -1.f;
    ov[(size_t)n*8+j] = o;
    atomicMax(&lmax[j], fkey(o));
  }
  __syncthreads();
  for (int i=tid;i<1024;i+=256) if (h[i]) atomicAdd(&hist10[i], h[i]);
  if (tid < 8) atomicMax(&gtmax[tid], lmax[tid]);
}

// ---------------- K4a: coarse threshold bucket ----------------
__global__ void hist_scan1(const u32* __restrict__ hist10, u32* __restrict__ meta)
{
  __shared__ u32 c[1024];
  const int t = threadIdx.x;
  c[t] = hist10[t];
  __syncthreads();
  if (t == 0) {
    u32 cum = 0;
    int b = 1023;
    for (; b > 0; --b) {
      if (cum + c[b] >= PRE) break;
      cum += c[b];
    }
    meta[0] = (u32)b;
    meta[1] = cum;
  }
}

// ---------------- K4b: refine hist + anchor labels (fused) ----------------
__global__ void refine_label(const u64* __restrict__ keys, const u32* __restrict__ meta,
                             u32* __restrict__ h64,
                             const float* __restrict__ ov, const u32* __restrict__ gtmax,
                             signed char* __restrict__ labels, signed char* __restrict__ amax,
                             int* __restrict__ exP)
{
  __shared__ u32 h[64];
  __shared__ int se[256];
  const int tid = threadIdx.x;
  if (tid < 64) h[tid] = 0;
  __syncthreads();
  const int n = blockIdx.x*256 + tid;
  const u32 sb = ~(u32)(keys[n] >> 32);
  if ((sb >> 22) == meta[0]) atomicAdd(&h[(sb >> 16) & 63], 1u);

  float best = -3.402823466e38f;
  int arg = 0;
  bool isbest = false;
#pragma unroll
  for (int j=0;j<8;j++) {
    const float o = ov[(size_t)n*8+j];
    if (o > best) { best = o; arg = j; }
    if (fkey(o) == gtmax[j]) isbest = true;
  }
  const bool inside = ov[(size_t)n*8+0] >= 0.f;
  int lab = -1;
  if (inside && best < 0.3f) lab = 0;
  if (inside && isbest) lab = 1;
  if (inside && best >= 0.7f) lab = 1;
  labels[n] = (signed char)lab;
  amax[n] = (signed char)arg;
  se[tid] = (lab >= 0) ? 1 : 0;
  __syncthreads();
  if (tid < 64 && h[tid]) atomicAdd(&h64[tid], h[tid]);
  for (int s=128; s>0; s>>=1) {
    if (tid < s) se[tid] += se[tid+s];
    __syncthreads();
  }
  if (tid==0) exP[blockIdx.x] = se[0];
}

// ---------------- K5: threshold recompute + compact + loss partials (fused) ----------------
__global__ void collect_loss(const u64* __restrict__ keys,
                             const u32* __restrict__ meta, const u32* __restrict__ h64,
                             u32* __restrict__ counter, u64* __restrict__ cand,
                             const float* __restrict__ cls_out, const float* __restrict__ bbox_out,
                             const float* __restrict__ gt, const signed char* __restrict__ labels,
                             const signed char* __restrict__ amax, float2* __restrict__ lossP)
{
#pragma clang fp contract(off)
  __shared__ float sce[256];
  __shared__ float sbx[256];
  __shared__ u32 sthr;
  const int tid = threadIdx.x;
  if (tid == 0) {
    u32 cum = meta[1];
    int s = 63;
    for (; s > 0; --s) { cum += h64[s]; if (cum >= PRE) break; }
    sthr = (meta[0] << 6) | (u32)s;
  }
  __syncthreads();
  const u32 thr = sthr;
  const int n = blockIdx.x*256 + tid;
  const u64 k = keys[n];
  const u32 sb = ~(u32)(k >> 32);
  if ((sb >> 16) >= thr) {
    u32 p = atomicAdd(counter, 1u);
    cand[p] = k;
  }
  const int hw = n/9, a = n - hw*9;
  const int lab = labels[n];
  float ce = 0.f, bx = 0.f;
  if (lab >= 0) {
    const float l0 = cls_out[a*HW+hw], l1 = cls_out[(9+a)*HW+hw];
    const float m = fmaxf(l0,l1);
    const float lse = m + logf(expf(l0-m)+expf(l1-m));
    ce = lse - (lab==1 ? l1 : l0);
  }
  if (lab == 1) {
    const int x = hw % HF, y = hw / HF;
    const float ax1 = BA[a][0]+16.f*(float)x, ay1 = BA[a][1]+16.f*(float)y;
    const float ax2 = BA[a][2]+16.f*(float)x, ay2 = BA[a][3]+16.f*(float)y;
    const float ew = ax2-ax1+1.f, eh = ay2-ay1+1.f;
    const float ecx = ax1+0.5f*ew, ecy = ay1+0.5f*eh;
    const int g = amax[n];
    const float g0=gt[g*5+0], g1=gt[g*5+1], g2=gt[g*5+2], g3=gt[g*5+3];
    const float gw = g2-g0+1.f, gh = g3-g1+1.f;
    const float gcx = g0+0.5f*gw, gcy = g1+0.5f*gh;
    float tgt[4];
    tgt[0] = (gcx-ecx)/ew;
    tgt[1] = (gcy-ecy)/eh;
    tgt[2] = logf(gw/ew);
    tgt[3] = logf(gh/eh);
#pragma unroll
    for (int j=0;j<4;j++) {
      const float d = bbox_out[(a*4+j)*HW+hw];
      const float diff = d - tgt[j];
      const float ad = fabsf(diff);
      bx += (ad < (1.0f/9.0f)) ? (4.5f*diff*diff) : (ad - 0.5f/9.0f);
    }
  }
  sce[tid]=ce; sbx[tid]=bx;
  __syncthreads();
  for (int s=128;s>0;s>>=1) {
    if (tid<s) { sce[tid]+=sce[tid+s]; sbx[tid]+=sbx[tid+s]; }
    __syncthreads();
  }
  if (tid==0) lossP[blockIdx.x] = make_float2(sce[0], sbx[0]);
}

// ---------------- K6a: partial ranks (j-parallel) ----------------
__global__ void rank_partial(const u64* __restrict__ cand, const u32* __restrict__ counter,
                             u32* __restrict__ rankbuf)
{
  __shared__ u64 sk[256];
  const int M = (int)counter[0];
  if (blockIdx.x*256 >= M) return;
  const int i = blockIdx.x*256 + threadIdx.x;
  const u64 key = (i < M) ? cand[i] : ~0ull;
  const int chunk = ((M + 7)/8 + 255) & ~255;
  const int j0 = blockIdx.y*chunk;
  const int j1 = (j0 + chunk < M) ? (j0 + chunk) : M;
  int rank = 0;
  for (int t0 = j0; t0 < j1; t0 += 256) {
    const int j = t0 + threadIdx.x;
    sk[threadIdx.x] = (j < M) ? cand[j] : ~0ull;
    __syncthreads();
    const int lim = (j1 - t0 < 256) ? (j1 - t0) : 256;
    for (int k=0;k<lim;k++) rank += (sk[k] < key) ? 1 : 0;
    __syncthreads();
  }
  if (i < M && rank) atomicAdd(&rankbuf[i], (u32)rank);
}

// ---------------- K6b: scatter by rank ----------------
__global__ void rank_scatter2(const u64* __restrict__ cand, const u32* __restrict__ counter,
                              const u32* __restrict__ rankbuf, const float4* __restrict__ props,
                              float4* __restrict__ sprops)
{
  const int M = (int)counter[0];
  const int i = blockIdx.x*256 + threadIdx.x;
  if (i >= M) return;
  const u32 r = rankbuf[i];
  if (r < PRE) sprops[r] = props[(u32)cand[i]];
}

// ---------------- K7: NMS suppression bitmask (256-thr blocks, upper triangle) ----------------
__global__ void nms_mask(const float4* __restrict__ sp, u64* __restrict__ mask)
{
#pragma clang fp contract(off)
  const int c0 = blockIdx.x * 64;
  const int r0 = blockIdx.y * 256;
  if (c0 + 63 < r0) return;
  __shared__ float4 cb[64];
  __shared__ float  ca[64];
  const int tid = threadIdx.x;
  const int cend = min(64, PRE - c0);
  if (tid < cend) {
    float4 b = sp[c0 + tid];
    cb[tid] = b;
    ca[tid] = (b.z-b.x+1.f)*(b.w-b.y+1.f);
  }
  __syncthreads();
  const int row = r0 + tid;
  if (row >= PRE) return;
  const float4 rb = sp[row];
  const float ra = (rb.z-rb.x+1.f)*(rb.w-rb.y+1.f);
  u64 bits = 0;
  for (int j=0;j<cend;j++) {
    const float4 c = cb[j];
    const float xx1 = fmaxf(rb.x, c.x), yy1 = fmaxf(rb.y, c.y);
    const float xx2 = fminf(rb.z, c.z), yy2 = fminf(rb.w, c.w);
    const float inter = fmaxf(xx2-xx1+1.f, 0.f) * fmaxf(yy2-yy1+1.f, 0.f);
    const float iou = inter / (ra + ca[j] - inter);
    if (iou > 0.7f) bits |= (1ull << j);
  }
  mask[(size_t)row*NW + blockIdx.x] = bits;
}

// ---------------- K8: fused {chunked NMS scan | loss_final | feat transpose} ----------------
// Chunked scan: selected indices are strictly increasing (first-set-bit of shrinking set),
// so process 512-box chunks: LDS-resident 512x8-word mask slice + batched application of
// prior selections; the serial chain reads LDS (~150cyc/iter) instead of L2 rows.
__global__ void fused_scan_tr(const u64* __restrict__ mask, const float4* __restrict__ sp,
                              float* __restrict__ rois,
                              const float2* __restrict__ lossP, const int* __restrict__ exP,
                              float* __restrict__ out,
                              const float* __restrict__ feat, float* __restrict__ featT, int doT)
{
  const int b = blockIdx.x;
  if (b == 0) {
    __shared__ u64 mslice[4096];     // 512 rows x 8 words (32 KB)
    __shared__ u64 vbits[8];
    __shared__ int keep_s[POST];
    __shared__ int s_nsel;
    const int tid = threadIdx.x;
    for (int i = tid; i < POST; i += 256) keep_s[i] = 0;
    if (tid == 0) s_nsel = 0;
    __syncthreads();
    for (int c = 0; c < 24; ++c) {
      if (s_nsel >= POST) break;                 // uniform (post-barrier value)
      const int base = c * 512;
      const int cnt = (PRE - base < 512) ? (PRE - base) : 512;   // 512 or 224
      if (tid < 8) {
        u64 v = 0;
        const int lo = tid * 64;
        if (lo < cnt) {
          v = ~0ull;
          const int rem = cnt - lo;
          if (rem < 64) v = (1ull << rem) - 1ull;
        }
        vbits[tid] = v;
      }
      __syncthreads();
      for (int k = tid; k < cnt*8; k += 256) {
        const int i = k >> 3, w = k & 7;
        mslice[k] = mask[(size_t)(base + i)*NW + c*8 + w];
      }
      const int ns = s_nsel;
      for (int k = tid; k < ns*8; k += 256) {
        const int s = k >> 3, w = k & 7;
        const u64 row = mask[(size_t)keep_s[s]*NW + c*8 + w];
        if (row) atomicAnd(&vbits[w], ~row);
      }
      __syncthreads();
      if (tid < 64) {
        const int l = tid;
        u64 v = (l < 8) ? vbits[l] : 0;
        int nsel = s_nsel;
        for (;;) {
          const u64 bal = __ballot(v != 0);
          if (bal == 0) break;
          const int src = __ffsll((unsigned long long)bal) - 1;
          int fi = 0;
          if (v) fi = l*64 + __ffsll(v) - 1;
          const int il = __shfl(fi, src);
          if (l == 0) keep_s[nsel] = base + il;
          nsel++;
          if (nsel >= POST) break;
          if (l < 8) v &= ~mslice[(il << 3) | l];
        }
        if (l == 0) s_nsel = nsel;
      }
      __syncthreads();
    }
    for (int i = tid; i < POST; i += 256) {
      const float4 bb = sp[keep_s[i]];
      rois[i*5+0] = 0.f;
      rois[i*5+1] = bb.x; rois[i*5+2] = bb.y; rois[i*5+3] = bb.z; rois[i*5+4] = bb.w;
    }
  } else if (b == 1) {
    __shared__ float a[256];
    __shared__ float c[256];
    __shared__ int   e[256];
    const int t = threadIdx.x;
    float ax = 0.f, cx = 0.f; int ev = 0;
    if (t < NBLK) { float2 v = lossP[t]; ax = v.x; cx = v.y; ev = exP[t]; }
    if (t + 256 < NBLK) { float2 v = lossP[t+256]; ax += v.x; cx += v.y; ev += exP[t+256]; }
    a[t]=ax; c[t]=cx; e[t]=ev;
    __syncthreads();
    for (int s=128;s>0;s>>=1) {
      if (t<s) { a[t]+=a[t+s]; c[t]+=c[t+s]; e[t]+=e[t+s]; }
      __syncthreads();
    }
    if (t==0) {
      const float nex = (float)max(e[0], 1);
      out[OUT_POOL+0] = a[0] / nex;
      out[OUT_POOL+1] = c[0] / nex;
    }
  } else if (doT) {
    __shared__ float t[64][65];
    const int tt = b - 2;               // 0..2303
    const int bxhw = (tt % 144)*64, byc = (tt / 144)*64;
    const int tid = threadIdx.x;
    const int l = tid & 63, g = tid >> 6;
#pragma unroll
    for (int i=0;i<16;i++) {
      const int cL = g + 4*i;
      t[cL][l] = feat[(size_t)(byc+cL)*HW + bxhw + l];
    }
    __syncthreads();
#pragma unroll
    for (int i=0;i<16;i++) {
      const int hwL = g + 4*i;
      featT[(size_t)(bxhw+hwL)*1024 + byc + l] = t[l][hwL];
    }
  }
}

// ---------------- K9: ROI bilinear crop ----------------
struct __align__(16) Samp { int p0,p1,p2,p3; float w0,w1,w2,w3; };

__device__ __forceinline__ Samp make_samp(const float* __restrict__ rois, int r, int s)
{
#pragma clang fp contract(off)
  const int py = s / 7, px = s - py*7;
  const float x1 = rois[r*5+1] * 0.0625f;
  const float y1 = rois[r*5+2] * 0.0625f;
  const float x2 = rois[r*5+3] * 0.0625f;
  const float y2 = rois[r*5+4] * 0.0625f;
  const float t00 = (x2-x1)/95.f;
  const float t02 = (x1+x2-95.f)/95.f;
  const float t11 = (y2-y1)/95.f;
  const float t12 = (y1+y2-95.f)/95.f;
  const float lx = (float)(px-3)/3.f;
  const float ly = (float)(py-3)/3.f;
  const float gx = t00*lx + t02;
  const float gy = t11*ly + t12;
  const float ix = (gx+1.f)*0.5f*95.f;
  const float iy = (gy+1.f)*0.5f*95.f;
  const float ix0 = floorf(ix), iy0 = floorf(iy);
  const float wx = ix-ix0, wy = iy-iy0;
  const float xs[2] = {ix0, ix0+1.f};
  const float ys[2] = {iy0, iy0+1.f};
  const float wxs[2] = {1.f-wx, wx};
  const float wys[2] = {1.f-wy, wy};
  int pos[4]; float wt[4];
#pragma unroll
  for (int k=0;k<4;k++) {
    const int dy = k>>1, dx = k&1;
    const float yi = ys[dy], xi = xs[dx];
    const bool valid = (yi>=0.f)&&(yi<96.f)&&(xi>=0.f)&&(xi<96.f);
    const int yc = (int)fminf(fmaxf(yi,0.f),95.f);
    const int xc = (int)fminf(fmaxf(xi,0.f),95.f);
    pos[k] = yc*96+xc;
    wt[k] = wys[dy]*wxs[dx] * (valid?1.f:0.f);
  }
  Samp t;
  t.p0=pos[0]; t.p1=pos[1]; t.p2=pos[2]; t.p3=pos[3];
  t.w0=wt[0];  t.w1=wt[1];  t.w2=wt[2];  t.w3=wt[3];
  return t;
}

__global__ void roi_pool_coal(const float* __restrict__ featT, const float* __restrict__ rois,
                              float* __restrict__ out)
{
#pragma clang fp contract(off)
  __shared__ float st[49][257];
  __shared__ Samp sam[49];
  const int tid = threadIdx.x;
  const int r = blockIdx.x, cb = blockIdx.y;
  if (tid < 49) sam[tid] = make_samp(rois, r, tid);
  __syncthreads();
  const int c = cb*256 + tid;
  for (int s=0;s<49;s++) {
    const Samp t = sam[s];
    st[s][tid] = t.w0*featT[(size_t)t.p0*1024+c] + t.w1*featT[(size_t)t.p1*1024+c]
               + t.w2*featT[(size_t)t.p2*1024+c] + t.w3*featT[(size_t)t.p3*1024+c];
  }
  __syncthreads();
  float* ob = out + (size_t)r*50176 + cb*12544;
  for (int i=tid; i<12544; i+=256) {
    const int cL = i / 49, s = i - cL*49;
    ob[i] = st[s][cL];
  }
}

__global__ void roi_pool_gather(const float* __restrict__ feat, const float* __restrict__ rois,
                                float* __restrict__ out)
{
#pragma clang fp contract(off)
  const int o = blockIdx.x*256 + threadIdx.x;
  const int s  = o % 49;
  const int rc = o / 49;
  const int c = rc & (CIN-1);
  const int r = rc >> 10;
  const Samp t = make_samp(rois, r, s);
  const float* f = feat + (size_t)c*HW;
  out[o] = t.w0*f[t.p0] + t.w1*f[t.p1] + t.w2*f[t.p2] + t.w3*f[t.p3];
}

// ---------------- launcher ----------------
extern "C" void kernel_launch(void* const* d_in, const int* in_sizes, int n_in,
                              void* d_out, int out_size, void* d_ws, size_t ws_size,
                              hipStream_t stream)
{
  const float* feat    = (const float*)d_in[0];
  const float* gt      = (const float*)d_in[1];
  const float* im_info = (const float*)d_in[2];
  const float* rpn_w   = (const float*)d_in[3];
  const float* rpn_b   = (const float*)d_in[4];
  const float* cls_w   = (const float*)d_in[5];
  const float* cls_b   = (const float*)d_in[6];
  const float* bbox_w  = (const float*)d_in[7];
  const float* bbox_b  = (const float*)d_in[8];
  float* out = (float*)d_out;
  char* ws = (char*)d_ws;

  size_t off = 0;
  auto alloc = [&](size_t bytes) {
    size_t o = off;
    off = (off + bytes + 255) & ~(size_t)255;
    return o;
  };
  // zero-region (memset every call)
  size_t o_counter = alloc(4);
  size_t o_gtmax   = alloc(32);
  size_t o_meta    = alloc(8);
  size_t o_h64     = alloc(256);
  size_t o_hist10  = alloc(1024*4);
  size_t o_rank    = alloc((size_t)NA*4);
  size_t zeroBytes = off;
  // persistent across phases
  size_t o_cls  = alloc((size_t)18*HW*4);
  size_t o_bbox = alloc((size_t)36*HW*4);
  size_t o_rpn  = alloc((size_t)CMID*HW*4);
  // overlapped region R
  size_t o_R = off;
  const size_t IMG_BYTES  = (size_t)32*98*98*8*16;   // 39,337,984
  const size_t WBUF_BYTES = (size_t)9*2*128*512*16;  // 18,874,368
  const size_t FEATT_BYTES= (size_t)HW*1024*4;       // 37,748,736
  size_t o_img  = o_R;
  size_t o_wbuf = o_R + ((IMG_BYTES + 255) & ~(size_t)255);
  size_t baseC_A = o_R + ((FEATT_BYTES + 255) & ~(size_t)255);
  auto phaseC = [&](size_t base, size_t* offs) {
    size_t co = base;
    auto ca = [&](size_t bytes) { size_t o = co; co = (co + bytes + 255) & ~(size_t)255; return o; };
    offs[0] = ca((size_t)8*54*HW*4);          // partial (phase B)
    co = base;                                // phase C overlays partial
    offs[1] = ca((size_t)NA*8);               // keys
    offs[2] = ca((size_t)NA*16);              // props
    offs[3] = ca((size_t)NA*8);               // cand
    offs[4] = ca((size_t)PRE*16);             // sprops
    offs[5] = ca((size_t)PRE*NW*8);           // mask
    offs[6] = ca((size_t)POST*5*4);           // rois
    offs[7] = ca((size_t)NA*8*4);             // ov
    offs[8] = ca((size_t)NA);                 // labels
    offs[9] = ca((size_t)NA);                 // amax
    offs[10]= ca((size_t)NBLK*4);             // exP
    offs[11]= ca((size_t)NBLK*8);             // lossP
    size_t endC = co;
    size_t endB = base + (size_t)8*54*HW*4;
    return endC > endB ? endC : endB;
  };
  size_t offsA[12], offsB[12];
  size_t endA = phaseC(baseC_A, offsA);
  size_t convEnd = o_wbuf + WBUF_BYTES;
  size_t neededA = (endA > convEnd ? endA : convEnd);
  size_t endB = phaseC(o_R, offsB);
  (void)endB;
  const bool useT = (ws_size >= neededA);
  const size_t* offs = useT ? offsA : offsB;
  (void)in_sizes; (void)n_in; (void)out_size;

  hipMemsetAsync(ws, 0, zeroBytes, stream);

  f16x8* img      = (f16x8*)(ws + o_img);
  f16x8* wbuf     = (f16x8*)(ws + o_wbuf);
  float* featT    = (float*)(ws + o_R);
  float* partial  = (float*)(ws + offs[0]);
  float* rpn      = (float*)(ws + o_rpn);
  float* cls_out  = (float*)(ws + o_cls);
  float* bbox_out = (float*)(ws + o_bbox);
  u64*   keys     = (u64*)(ws + offs[1]);
  float4* props   = (float4*)(ws + offs[2]);
  u64*   cand     = (u64*)(ws + offs[3]);
  float4* sprops  = (float4*)(ws + offs[4]);
  u64*   maskp    = (u64*)(ws + offs[5]);
  float* rois     = (float*)(ws + offs[6]);
  float* ovp      = (float*)(ws + offs[7]);
  signed char* labels = (signed char*)(ws + offs[8]);
  signed char* amax   = (signed char*)(ws + offs[9]);
  int*    exP     = (int*)(ws + offs[10]);
  float2* lossP   = (float2*)(ws + offs[11]);
  u32* counter    = (u32*)(ws + o_counter);
  u32* gtmaxp     = (u32*)(ws + o_gtmax);
  u32* metap      = (u32*)(ws + o_meta);
  u32* h64p       = (u32*)(ws + o_h64);
  u32* hist10     = (u32*)(ws + o_hist10);
  u32* rankbuf    = (u32*)(ws + o_rank);

  // phase A: conv via split-fp16 MFMA
  prep_img<<<dim3(98,32), 256, 0, stream>>>(feat, img);
  prep_w<<<dim3(8,32), 256, 0, stream>>>(rpn_w, wbuf);
  rpn_conv_mfma<<<dim3(2,96,4), 128, 0, stream>>>(img, wbuf, rpn_b, rpn);
  // phase B: 1x1 convs
  conv1x1p<<<dim3(36,8), 256, 0, stream>>>(rpn, cls_w, bbox_w, partial);
  conv1x1r<<<54*HW/256, 256, 0, stream>>>(partial, cls_b, bbox_b, cls_out, bbox_out);
  // phase C: proposals + anchor targets
  score_decode_ov<<<NBLK, 256, 0, stream>>>(cls_out, bbox_out, im_info, gt,
                                            keys, props, hist10, ovp, gtmaxp);
  hist_scan1<<<1, 1024, 0, stream>>>(hist10, metap);
  refine_label<<<NBLK, 256, 0, stream>>>(keys, metap, h64p, ovp, gtmaxp, labels, amax, exP);
  collect_loss<<<NBLK, 256, 0, stream>>>(keys, metap, h64p, counter, cand,
                                         cls_out, bbox_out, gt, labels, amax, lossP);
  rank_partial<<<dim3(NBLK,8), 256, 0, stream>>>(cand, counter, rankbuf);
  rank_scatter2<<<NBLK, 256, 0, stream>>>(cand, counter, rankbuf, props, sprops);
  nms_mask<<<dim3(NW, 47), 256, 0, stream>>>(sprops, maskp);
  fused_scan_tr<<<2306, 256, 0, stream>>>(maskp, sprops, rois, lossP, exP, out,
                                          feat, featT, useT ? 1 : 0);
  if (useT) roi_pool_coal<<<dim3(POST,4), 256, 0, stream>>>(featT, rois, out);
  else      roi_pool_gather<<<OUT_POOL/256, 256, 0, stream>>>(feat, rois, out);
}